// Round 10
// baseline (291.900 us; speedup 1.0000x reference)
//
#include <hip/hip_runtime.h>

typedef _Float16 f16x8 __attribute__((ext_vector_type(8)));
typedef __fp16 fp16x2 __attribute__((ext_vector_type(2)));
typedef unsigned short u16x4 __attribute__((ext_vector_type(4)));
typedef float f32x4 __attribute__((ext_vector_type(4)));

#define VMWAIT(N) asm volatile("s_waitcnt vmcnt(" #N ")" ::: "memory")
#define LGKM0()   asm volatile("s_waitcnt lgkmcnt(0)" ::: "memory")
#define FENCE()   asm volatile("" ::: "memory")
#define RBAR()    do { FENCE(); __builtin_amdgcn_s_barrier(); FENCE(); } while (0)

__device__ __forceinline__ void gload_lds16(const void* gsrc, void* ldst) {
    __builtin_amdgcn_global_load_lds(
        (const unsigned int __attribute__((address_space(1)))*)gsrc,
        (unsigned int __attribute__((address_space(3)))*)ldst,
        16, 0, 0);
}

__device__ __forceinline__ u16x4 cvt4(float4 v) {
    u16x4 h;
    h[0] = __builtin_bit_cast(unsigned short, (_Float16)v.x);
    h[1] = __builtin_bit_cast(unsigned short, (_Float16)v.y);
    h[2] = __builtin_bit_cast(unsigned short, (_Float16)v.z);
    h[3] = __builtin_bit_cast(unsigned short, (_Float16)v.w);
    return h;
}

// ---------------------------------------------------------------------------
// Kernel 0: W [K,U] f32 -> fp16 image, layout [ktile=k>>5][u][k&31] u16.
// ---------------------------------------------------------------------------
__global__ void convert_w_kernel(const float* __restrict__ w1,
                                 const float* __restrict__ w2,
                                 unsigned short* __restrict__ w1img,
                                 unsigned short* __restrict__ w2img) {
    int u = blockIdx.x;
    int k = threadIdx.x + blockIdx.y * 256;
    size_t idx = (size_t)(k >> 5) * 16384 + (size_t)u * 32 + (k & 31);
    _Float16 h1 = (_Float16)w1[(size_t)k * 512 + u];
    _Float16 h2 = (_Float16)w2[(size_t)k * 512 + u];
    w1img[idx] = __builtin_bit_cast(unsigned short, h1);
    w2img[idx] = __builtin_bit_cast(unsigned short, h2);
}

// ---------------------------------------------------------------------------
// h2 kernel (round-5 structure, grid (32,2))
// ---------------------------------------------------------------------------
__device__ __forceinline__ void stage_a64(const float* __restrict__ src,
                                          char* As, int tid) {
    const int row = tid >> 2, q = tid & 3;
    const float* p = src + (size_t)row * 512 + q * 4;
    const int sw2 = ((row >> 1) & 3) << 4;
    char* wb = As + row * 64;
    float4 va[4], vb[4];
#define AISS(V, G) { _Pragma("unroll") \
    for (int j_ = 0; j_ < 4; ++j_) V[j_] = *(const float4*)(p + ((G) * 4 + j_) * 16); }
#define APRC(V, G) { _Pragma("unroll") \
    for (int j_ = 0; j_ < 4; ++j_) { \
        const int i_ = (G) * 4 + j_; \
        *(u16x4*)(wb + (i_ >> 1) * 4096 + ((q * 8 + (i_ & 1) * 32) ^ sw2)) = cvt4(V[j_]); } }
    AISS(va, 0); AISS(vb, 1);
    VMWAIT(4); APRC(va, 0); AISS(va, 2);
    VMWAIT(4); APRC(vb, 1); AISS(vb, 3);
    VMWAIT(4); APRC(va, 2); AISS(va, 4);
    VMWAIT(4); APRC(vb, 3); AISS(vb, 5);
    VMWAIT(4); APRC(va, 4); AISS(va, 6);
    VMWAIT(4); APRC(vb, 5); AISS(vb, 7);
    VMWAIT(4); APRC(va, 6);
    VMWAIT(0); APRC(vb, 7);
#undef AISS
#undef APRC
}

__device__ __forceinline__ void chunk_gemm(const char* __restrict__ bcol,
                                           const char* As, const int* aoff,
                                           f32x4 acc[4][4]) {
    f16x8 brA[4], brB[4], afA[4], afB[4];
    #pragma unroll
    for (int i = 0; i < 4; ++i)
        #pragma unroll
        for (int j = 0; j < 4; ++j) acc[i][j] = (f32x4){0.f, 0.f, 0.f, 0.f};
    #pragma unroll
    for (int j = 0; j < 4; ++j) brA[j] = *(const f16x8*)(bcol + j * 1024);
    #pragma unroll
    for (int j = 0; j < 4; ++j) brB[j] = *(const f16x8*)(bcol + 32768 + j * 1024);
    #pragma unroll
    for (int i = 0; i < 4; ++i) afA[i] = *(const f16x8*)(As + aoff[i]);
    #pragma unroll
    for (int tt = 0; tt < 8; ++tt) {
        const int t0 = 2 * tt, t1 = t0 + 1;
        #pragma unroll
        for (int i = 0; i < 4; ++i)
            afB[i] = *(const f16x8*)(As + t1 * 4096 + aoff[i]);
        VMWAIT(4);
        #pragma unroll
        for (int i = 0; i < 4; ++i)
            #pragma unroll
            for (int j = 0; j < 4; ++j)
                acc[i][j] = __builtin_amdgcn_mfma_f32_16x16x32_f16(afA[i], brA[j], acc[i][j], 0, 0, 0);
        if (t0 < 14) {
            #pragma unroll
            for (int j = 0; j < 4; ++j)
                brA[j] = *(const f16x8*)(bcol + (t0 + 2) * 32768 + j * 1024);
        }
        if (t1 < 15) {
            #pragma unroll
            for (int i = 0; i < 4; ++i)
                afA[i] = *(const f16x8*)(As + (t1 + 1) * 4096 + aoff[i]);
        }
        if (t1 < 14) { VMWAIT(4); } else { VMWAIT(0); }
        #pragma unroll
        for (int i = 0; i < 4; ++i)
            #pragma unroll
            for (int j = 0; j < 4; ++j)
                acc[i][j] = __builtin_amdgcn_mfma_f32_16x16x32_f16(afB[i], brB[j], acc[i][j], 0, 0, 0);
        if (t1 < 14) {
            #pragma unroll
            for (int j = 0; j < 4; ++j)
                brB[j] = *(const f16x8*)(bcol + (t1 + 2) * 32768 + j * 1024);
        }
    }
}

__global__ __launch_bounds__(256, 2)
void h2_gemm_kernel(const float* __restrict__ hidden,
                    const char* __restrict__ w2img,
                    const float* __restrict__ b2,
                    float* __restrict__ h2o) {
    __shared__ char As[65536];
    const int tid = threadIdx.x, bm = blockIdx.x, bn = blockIdx.y;
    const int lane = tid & 63, wid = tid >> 6;
    const int lane16 = lane & 15, g = lane >> 4;
    stage_a64(hidden + (size_t)bm * 32768, As, tid);
    __syncthreads();
    int aoff[4];
    #pragma unroll
    for (int i = 0; i < 4; ++i)
        aoff[i] = (i * 16 + lane16) * 64 + ((g ^ ((lane16 >> 1) & 3)) << 4);
    const char* bcol = w2img + (size_t)(bn * 256 + wid * 64 + lane16) * 64 + g * 16;
    f32x4 acc[4][4];
    chunk_gemm(bcol, As, aoff, acc);
    #pragma unroll
    for (int j = 0; j < 4; ++j) {
        int col = bn * 256 + wid * 64 + j * 16 + lane16;
        float bb = b2[col];
        #pragma unroll
        for (int i = 0; i < 4; ++i)
            #pragma unroll
            for (int r = 0; r < 4; ++r)
                h2o[(size_t)(bm * 64 + i * 16 + g * 4 + r) * 512 + col] = acc[i][j][r] + bb;
    }
}

// ---------------------------------------------------------------------------
// Fused kernel: 256 blocks x 8 batches, 512 thr (8 waves), 1 block/CU.
// A: 16-slot x 8KB fp32 LDS ring via global_load_lds, 12-step lead.
// B: W1 fp16 image global->reg, DEPTH-4 rotation (16 steps % 4 == 0, so the
//    slot assignment is batch-boundary consistent — depth 3 was the r9 bug).
// Per step: VMWAIT(10) -> s_barrier -> ds_read fp32 -> cvt_pkrtz -> 16 MFMA
// -> issue 1 A-refill + 4 B loads. Context reads feat from global (L2-hot).
// ---------------------------------------------------------------------------
__global__ __launch_bounds__(512, 2)
void fused_all_kernel(const float* __restrict__ feat,
                      const char* __restrict__ w1img,
                      const float* __restrict__ h2,
                      const float* __restrict__ b1,
                      const float* __restrict__ wv,
                      float* __restrict__ out) {
    __shared__ char ring[131072];
    __shared__ float hhs[8 * 512];
    __shared__ float wvs[512];
    __shared__ float spl[64 * 8];
    __shared__ float wsm[64];

    const int tid = threadIdx.x;
    const int lane16 = tid & 15, g = (tid >> 4) & 3;
    const int wid = tid >> 6;
    const int b0 = blockIdx.x * 8;
    const int r7 = lane16 & 7;

    // ---- prologue: constants into LDS (before the vm ledger starts) ----
    {
        float bb = b1[tid];
        wvs[tid] = wv[tid];
        #pragma unroll
        for (int it = 0; it < 8; ++it)
            hhs[it * 512 + tid] = bb + h2[(size_t)(b0 + it) * 512 + tid];
    }
    const int arow = tid >> 3, aslot = tid & 7;
    const size_t asrc0 = (size_t)arow * 2048 + ((size_t)(aslot ^ (arow & 7)) << 4);
    const char* fb = (const char*)feat;

    VMWAIT(0);   // ledger clean
    FENCE();
    #pragma unroll
    for (int u = 0; u < 12; ++u)
        gload_lds16(fb + (size_t)b0 * 131072 + (size_t)u * 128 + asrc0,
                    ring + u * 8192 + tid * 16);
    FENCE();
    f16x8 bf[4][4];
    #pragma unroll
    for (int q = 0; q < 3; ++q) {
        #pragma unroll
        for (int j = 0; j < 4; ++j)
            bf[q][j] = *(const f16x8*)(w1img + (size_t)q * 32768 +
                        (size_t)(wid * 64 + j * 16 + lane16) * 64 + g * 16);
        FENCE();
    }
    LGKM0();
    RBAR();

    // ---- batch loop ----
    #pragma unroll 1
    for (int it = 0; it < 8; ++it) {
        f32x4 acc[4][4];
        #pragma unroll
        for (int i = 0; i < 4; ++i)
            #pragma unroll
            for (int j = 0; j < 4; ++j) acc[i][j] = (f32x4){0.f, 0.f, 0.f, 0.f};
        float hhv[4], wvv[4];
        #pragma unroll
        for (int j = 0; j < 4; ++j) {
            int col = wid * 64 + j * 16 + lane16;
            hhv[j] = hhs[it * 512 + col];
            wvv[j] = wvs[col];
        }

        #pragma unroll
        for (int t = 0; t < 16; ++t) {
            VMWAIT(10);
            RBAR();
            f16x8 af[4];
            #pragma unroll
            for (int i = 0; i < 4; ++i) {
                const char* base = ring + t * 8192 + (i * 16 + lane16) * 128;
                float4 lo = *(const float4*)(base + (((2 * g + 0) ^ r7) << 4));
                float4 hi = *(const float4*)(base + (((2 * g + 1) ^ r7) << 4));
                union { fp16x2 p[4]; f16x8 v; } uu;
                uu.p[0] = __builtin_amdgcn_cvt_pkrtz(lo.x, lo.y);
                uu.p[1] = __builtin_amdgcn_cvt_pkrtz(lo.z, lo.w);
                uu.p[2] = __builtin_amdgcn_cvt_pkrtz(hi.x, hi.y);
                uu.p[3] = __builtin_amdgcn_cvt_pkrtz(hi.z, hi.w);
                af[i] = uu.v;
            }
            __builtin_amdgcn_s_setprio(1);
            #pragma unroll
            for (int i = 0; i < 4; ++i)
                #pragma unroll
                for (int j = 0; j < 4; ++j)
                    acc[i][j] = __builtin_amdgcn_mfma_f32_16x16x32_f16(af[i], bf[t & 3][j], acc[i][j], 0, 0, 0);
            __builtin_amdgcn_s_setprio(0);
            FENCE();
            {   // A-refill: slot (t+12)&15 with next-relevant batch's ktile
                const int u_ = (t + 12) & 15;
                const int bn = b0 + ((it + (t >= 4 ? 1 : 0)) & 7);
                gload_lds16(fb + (size_t)bn * 131072 + (size_t)u_ * 128 + asrc0,
                            ring + u_ * 8192 + tid * 16);
            }
            FENCE();
            {   // B-refill: ktile (t+3)&15 into rotation slot (t+3)&3
                const int q = (t + 3) & 3, kt = (t + 3) & 15;
                #pragma unroll
                for (int j = 0; j < 4; ++j)
                    bf[q][j] = *(const f16x8*)(w1img + (size_t)kt * 32768 +
                                (size_t)(wid * 64 + j * 16 + lane16) * 64 + g * 16);
            }
            FENCE();
        }

        // ---- epilogue: scores -> softmax -> context -> out ----
        #pragma unroll
        for (int i = 0; i < 4; ++i)
            #pragma unroll
            for (int r = 0; r < 4; ++r) {
                float s = 0.f;
                #pragma unroll
                for (int j = 0; j < 4; ++j) {
                    float h = acc[i][j][r] + hhv[j];
                    float ex = __expf(2.f * h);
                    s += (1.f - 2.f * __builtin_amdgcn_rcpf(ex + 1.f)) * wvv[j];
                }
                s += __shfl_xor(s, 1); s += __shfl_xor(s, 2);
                s += __shfl_xor(s, 4); s += __shfl_xor(s, 8);
                if (lane16 == 0) spl[(i * 16 + g * 4 + r) * 8 + wid] = s;
            }
        LGKM0();
        RBAR();
        if (tid < 64) {
            float s = ((spl[tid * 8 + 0] + spl[tid * 8 + 1]) + (spl[tid * 8 + 2] + spl[tid * 8 + 3])) +
                      ((spl[tid * 8 + 4] + spl[tid * 8 + 5]) + (spl[tid * 8 + 6] + spl[tid * 8 + 7]));
            float m = s;
            #pragma unroll
            for (int off = 32; off; off >>= 1) m = fmaxf(m, __shfl_xor(m, off));
            float e = __expf(s - m);
            float sum = e;
            #pragma unroll
            for (int off = 32; off; off >>= 1) sum += __shfl_xor(sum, off);
            wsm[tid] = e / sum;
        }
        LGKM0();
        RBAR();
        {   // context from global (L2/L3-hot): col = tid, 64 seq rows
            const float* fr = feat + (size_t)(b0 + it) * 32768 + tid;
            float v0[16], v1[16], a = 0.f;
            #pragma unroll
            for (int s2 = 0; s2 < 16; ++s2) v0[s2] = fr[s2 * 512];
            FENCE();
            #pragma unroll
            for (int s2 = 0; s2 < 16; ++s2) v1[s2] = fr[(16 + s2) * 512];
            FENCE();
            VMWAIT(16);
            #pragma unroll
            for (int s2 = 0; s2 < 16; ++s2) a += wsm[s2] * v0[s2];
            #pragma unroll
            for (int s2 = 0; s2 < 16; ++s2) v0[s2] = fr[(32 + s2) * 512];
            FENCE();
            VMWAIT(16);
            #pragma unroll
            for (int s2 = 0; s2 < 16; ++s2) a += wsm[16 + s2] * v1[s2];
            #pragma unroll
            for (int s2 = 0; s2 < 16; ++s2) v1[s2] = fr[(48 + s2) * 512];
            FENCE();
            VMWAIT(16);
            #pragma unroll
            for (int s2 = 0; s2 < 16; ++s2) a += wsm[32 + s2] * v0[s2];
            VMWAIT(0);
            #pragma unroll
            for (int s2 = 0; s2 < 16; ++s2) a += wsm[48 + s2] * v1[s2];
            out[(size_t)(b0 + it) * 512 + tid] = a;
        }
        FENCE();
    }
}

// ---------------------------------------------------------------------------
extern "C" void kernel_launch(void* const* d_in, const int* in_sizes, int n_in,
                              void* d_out, int out_size, void* d_ws, size_t ws_size,
                              hipStream_t stream) {
    (void)in_sizes; (void)n_in; (void)out_size; (void)ws_size;
    const float* feat   = (const float*)d_in[0];   // [2048,64,512]
    const float* hidden = (const float*)d_in[1];   // [2048,512]
    const float* W1     = (const float*)d_in[2];   // [512,512]
    const float* b1     = (const float*)d_in[3];   // [512]
    const float* W2     = (const float*)d_in[4];   // [512,512]
    const float* b2     = (const float*)d_in[5];   // [512]
    const float* Wv     = (const float*)d_in[6];   // [512,1]
    // d_in[7] = bv: softmax shift-invariant, unused.
    float* out = (float*)d_out;                    // [2048,512]

    char* ws = (char*)d_ws;
    unsigned short* w1img = (unsigned short*)(ws);            // 512 KB
    unsigned short* w2img = (unsigned short*)(ws + 524288);   // 512 KB
    float* h2 = (float*)(ws + 1048576);                       // 4 MB

    convert_w_kernel<<<dim3(512, 2), dim3(256), 0, stream>>>(W1, W2, w1img, w2img);
    h2_gemm_kernel<<<dim3(32, 2), dim3(256), 0, stream>>>(hidden, (const char*)w2img, b2, h2);
    fused_all_kernel<<<dim3(256), dim3(512), 0, stream>>>(feat, (const char*)w1img, h2, b1, Wv, out);
}

// Round 11
// 142.281 us; speedup vs baseline: 2.0516x; 2.0516x over previous
//
#include <hip/hip_runtime.h>

typedef _Float16 f16x8 __attribute__((ext_vector_type(8)));
typedef unsigned short u16x4 __attribute__((ext_vector_type(4)));
typedef float f32x4 __attribute__((ext_vector_type(4)));

#define VMWAIT(N) asm volatile("s_waitcnt vmcnt(" #N ")" ::: "memory")
#define LGKM0()   asm volatile("s_waitcnt lgkmcnt(0)" ::: "memory")
#define FENCE()   asm volatile("" ::: "memory")
#define RBAR()    do { FENCE(); __builtin_amdgcn_s_barrier(); FENCE(); } while (0)

__device__ __forceinline__ u16x4 cvt4(float4 v) {
    u16x4 h;
    h[0] = __builtin_bit_cast(unsigned short, (_Float16)v.x);
    h[1] = __builtin_bit_cast(unsigned short, (_Float16)v.y);
    h[2] = __builtin_bit_cast(unsigned short, (_Float16)v.z);
    h[3] = __builtin_bit_cast(unsigned short, (_Float16)v.w);
    return h;
}

// ---------------------------------------------------------------------------
// Kernel 0: W [K,U] f32 -> fp16 image, layout [ktile=k>>5][u][k&31] u16.
// ---------------------------------------------------------------------------
__global__ void convert_w_kernel(const float* __restrict__ w1,
                                 const float* __restrict__ w2,
                                 unsigned short* __restrict__ w1img,
                                 unsigned short* __restrict__ w2img) {
    int u = blockIdx.x;
    int k = threadIdx.x + blockIdx.y * 256;
    size_t idx = (size_t)(k >> 5) * 16384 + (size_t)u * 32 + (k & 31);
    _Float16 h1 = (_Float16)w1[(size_t)k * 512 + u];
    _Float16 h2 = (_Float16)w2[(size_t)k * 512 + u];
    w1img[idx] = __builtin_bit_cast(unsigned short, h1);
    w2img[idx] = __builtin_bit_cast(unsigned short, h2);
}

// ---------------------------------------------------------------------------
// h2 kernel (round-5 structure, grid (32,2)) — unchanged, small cost
// ---------------------------------------------------------------------------
__device__ __forceinline__ void stage_a64(const float* __restrict__ src,
                                          char* As, int tid) {
    const int row = tid >> 2, q = tid & 3;
    const float* p = src + (size_t)row * 512 + q * 4;
    const int sw2 = ((row >> 1) & 3) << 4;
    char* wb = As + row * 64;
    float4 va[4], vb[4];
#define AISS(V, G) { _Pragma("unroll") \
    for (int j_ = 0; j_ < 4; ++j_) V[j_] = *(const float4*)(p + ((G) * 4 + j_) * 16); }
#define APRC(V, G) { _Pragma("unroll") \
    for (int j_ = 0; j_ < 4; ++j_) { \
        const int i_ = (G) * 4 + j_; \
        *(u16x4*)(wb + (i_ >> 1) * 4096 + ((q * 8 + (i_ & 1) * 32) ^ sw2)) = cvt4(V[j_]); } }
    AISS(va, 0); AISS(vb, 1);
    VMWAIT(4); APRC(va, 0); AISS(va, 2);
    VMWAIT(4); APRC(vb, 1); AISS(vb, 3);
    VMWAIT(4); APRC(va, 2); AISS(va, 4);
    VMWAIT(4); APRC(vb, 3); AISS(vb, 5);
    VMWAIT(4); APRC(va, 4); AISS(va, 6);
    VMWAIT(4); APRC(vb, 5); AISS(vb, 7);
    VMWAIT(4); APRC(va, 6);
    VMWAIT(0); APRC(vb, 7);
#undef AISS
#undef APRC
}

__device__ __forceinline__ void chunk_gemm(const char* __restrict__ bcol,
                                           const char* As, const int* aoff,
                                           f32x4 acc[4][4]) {
    f16x8 brA[4], brB[4], afA[4], afB[4];
    #pragma unroll
    for (int i = 0; i < 4; ++i)
        #pragma unroll
        for (int j = 0; j < 4; ++j) acc[i][j] = (f32x4){0.f, 0.f, 0.f, 0.f};
    #pragma unroll
    for (int j = 0; j < 4; ++j) brA[j] = *(const f16x8*)(bcol + j * 1024);
    #pragma unroll
    for (int j = 0; j < 4; ++j) brB[j] = *(const f16x8*)(bcol + 32768 + j * 1024);
    #pragma unroll
    for (int i = 0; i < 4; ++i) afA[i] = *(const f16x8*)(As + aoff[i]);
    #pragma unroll
    for (int tt = 0; tt < 8; ++tt) {
        const int t0 = 2 * tt, t1 = t0 + 1;
        #pragma unroll
        for (int i = 0; i < 4; ++i)
            afB[i] = *(const f16x8*)(As + t1 * 4096 + aoff[i]);
        VMWAIT(4);
        #pragma unroll
        for (int i = 0; i < 4; ++i)
            #pragma unroll
            for (int j = 0; j < 4; ++j)
                acc[i][j] = __builtin_amdgcn_mfma_f32_16x16x32_f16(afA[i], brA[j], acc[i][j], 0, 0, 0);
        if (t0 < 14) {
            #pragma unroll
            for (int j = 0; j < 4; ++j)
                brA[j] = *(const f16x8*)(bcol + (t0 + 2) * 32768 + j * 1024);
        }
        if (t1 < 15) {
            #pragma unroll
            for (int i = 0; i < 4; ++i)
                afA[i] = *(const f16x8*)(As + (t1 + 1) * 4096 + aoff[i]);
        }
        if (t1 < 14) { VMWAIT(4); } else { VMWAIT(0); }
        #pragma unroll
        for (int i = 0; i < 4; ++i)
            #pragma unroll
            for (int j = 0; j < 4; ++j)
                acc[i][j] = __builtin_amdgcn_mfma_f32_16x16x32_f16(afB[i], brB[j], acc[i][j], 0, 0, 0);
        if (t1 < 14) {
            #pragma unroll
            for (int j = 0; j < 4; ++j)
                brB[j] = *(const f16x8*)(bcol + (t1 + 2) * 32768 + j * 1024);
        }
    }
}

__global__ __launch_bounds__(256, 2)
void h2_gemm_kernel(const float* __restrict__ hidden,
                    const char* __restrict__ w2img,
                    const float* __restrict__ b2,
                    float* __restrict__ h2o) {
    __shared__ char As[65536];
    const int tid = threadIdx.x, bm = blockIdx.x, bn = blockIdx.y;
    const int lane = tid & 63, wid = tid >> 6;
    const int lane16 = lane & 15, g = lane >> 4;
    stage_a64(hidden + (size_t)bm * 32768, As, tid);
    __syncthreads();
    int aoff[4];
    #pragma unroll
    for (int i = 0; i < 4; ++i)
        aoff[i] = (i * 16 + lane16) * 64 + ((g ^ ((lane16 >> 1) & 3)) << 4);
    const char* bcol = w2img + (size_t)(bn * 256 + wid * 64 + lane16) * 64 + g * 16;
    f32x4 acc[4][4];
    chunk_gemm(bcol, As, aoff, acc);
    #pragma unroll
    for (int j = 0; j < 4; ++j) {
        int col = bn * 256 + wid * 64 + j * 16 + lane16;
        float bb = b2[col];
        #pragma unroll
        for (int i = 0; i < 4; ++i)
            #pragma unroll
            for (int r = 0; r < 4; ++r)
                h2o[(size_t)(bm * 64 + i * 16 + g * 4 + r) * 512 + col] = acc[i][j][r] + bb;
    }
}

// ---------------------------------------------------------------------------
// Single-set-A chunk GEMM (lower VGPR for the 128-cap fused kernel):
// per ktile: ds_read af (no dbuf) -> VMWAIT -> 16 MFMA -> refill B (2-deep).
// ---------------------------------------------------------------------------
__device__ __forceinline__ void chunk64_lowreg(const char* __restrict__ bcol,
                                               const char* As, const int* aoff,
                                               f32x4 acc[4][4]) {
    f16x8 brE[4], brO[4];
    #pragma unroll
    for (int i = 0; i < 4; ++i)
        #pragma unroll
        for (int j = 0; j < 4; ++j) acc[i][j] = (f32x4){0.f, 0.f, 0.f, 0.f};
    #pragma unroll
    for (int j = 0; j < 4; ++j) brE[j] = *(const f16x8*)(bcol + j * 1024);
    #pragma unroll
    for (int j = 0; j < 4; ++j) brO[j] = *(const f16x8*)(bcol + 32768 + j * 1024);
    #pragma unroll
    for (int t = 0; t < 16; ++t) {
        f16x8 af[4];
        #pragma unroll
        for (int i = 0; i < 4; ++i)
            af[i] = *(const f16x8*)(As + t * 4096 + aoff[i]);
        if (t < 14) { VMWAIT(4); } else { VMWAIT(0); }
        LGKM0();
        if ((t & 1) == 0) {
            #pragma unroll
            for (int i = 0; i < 4; ++i)
                #pragma unroll
                for (int j = 0; j < 4; ++j)
                    acc[i][j] = __builtin_amdgcn_mfma_f32_16x16x32_f16(af[i], brE[j], acc[i][j], 0, 0, 0);
            FENCE();
            if (t < 14) {
                #pragma unroll
                for (int j = 0; j < 4; ++j)
                    brE[j] = *(const f16x8*)(bcol + (t + 2) * 32768 + j * 1024);
            }
        } else {
            #pragma unroll
            for (int i = 0; i < 4; ++i)
                #pragma unroll
                for (int j = 0; j < 4; ++j)
                    acc[i][j] = __builtin_amdgcn_mfma_f32_16x16x32_f16(af[i], brO[j], acc[i][j], 0, 0, 0);
            FENCE();
            if (t < 14) {
                #pragma unroll
                for (int j = 0; j < 4; ++j)
                    brO[j] = *(const f16x8*)(bcol + (t + 2) * 32768 + j * 1024);
            }
        }
        FENCE();
    }
}

// ---------------------------------------------------------------------------
// Fused kernel: 2048 blocks x 1 batch, 512 thr (8 waves), 2 blocks/CU ->
// 4 waves/SIMD (2x round-5 TLP). Wave wid owns cols [wid*64, +64).
// stage A (fp32->fp16 LDS, XOR-swz) -> chunk64 -> tanh·Wv -> softmax ->
// context from LDS (split across thread halves).
// ---------------------------------------------------------------------------
__global__ __launch_bounds__(512, 4)
void fused_all_kernel(const float* __restrict__ feat,
                      const char* __restrict__ w1img,
                      const float* __restrict__ h2,
                      const float* __restrict__ b1,
                      const float* __restrict__ wv,
                      float* __restrict__ out) {
    __shared__ char As[65536];
    __shared__ float spl[64 * 8];
    __shared__ float wsm[64];
    __shared__ float cpart[512];

    const int tid = threadIdx.x, bm = blockIdx.x;
    const int lane16 = tid & 15, g = (tid >> 4) & 3;
    const int wid = tid >> 6;

    // ---- stage: 512 thr, thread (row=tid>>3, q=tid&7), 16 float4 loads ----
    {
        const int row = tid >> 3, q = tid & 7;
        const float* p = feat + (size_t)bm * 32768 + (size_t)row * 512 + q * 4;
        char* wb = As + row * 64 + (((q >> 1) ^ ((row >> 1) & 3)) << 4) + (q & 1) * 8;
        float4 va[4], vb[4];
#define AISS(V, G) { _Pragma("unroll") \
    for (int j_ = 0; j_ < 4; ++j_) V[j_] = *(const float4*)(p + ((G) * 4 + j_) * 32); }
#define APRC(V, G) { _Pragma("unroll") \
    for (int j_ = 0; j_ < 4; ++j_) *(u16x4*)(wb + ((G) * 4 + j_) * 4096) = cvt4(V[j_]); }
        AISS(va, 0); AISS(vb, 1);
        VMWAIT(4); APRC(va, 0); AISS(va, 2);
        VMWAIT(4); APRC(vb, 1); AISS(vb, 3);
        VMWAIT(4); APRC(va, 2);
        VMWAIT(0); APRC(vb, 3);
#undef AISS
#undef APRC
    }
    LGKM0();
    RBAR();

    // ---- GEMM: wave owns 64 cols ----
    int aoff[4];
    #pragma unroll
    for (int i = 0; i < 4; ++i)
        aoff[i] = (i * 16 + lane16) * 64 + ((g ^ ((lane16 >> 1) & 3)) << 4);
    const char* bcol = w1img + (size_t)(wid * 64 + lane16) * 64 + g * 16;
    f32x4 acc[4][4];
    chunk64_lowreg(bcol, As, aoff, acc);

    // epilogue constants (FIFO clean after chunk's VMWAIT(0))
    float hhv[4], wvv[4];
    #pragma unroll
    for (int j = 0; j < 4; ++j) {
        int col = wid * 64 + j * 16 + lane16;
        hhv[j] = b1[col] + h2[(size_t)bm * 512 + col];
        wvv[j] = wv[col];
    }

    // ---- scores: tanh + dot(Wv) ----
    #pragma unroll
    for (int i = 0; i < 4; ++i)
        #pragma unroll
        for (int r = 0; r < 4; ++r) {
            float s = 0.f;
            #pragma unroll
            for (int j = 0; j < 4; ++j) {
                float h = acc[i][j][r] + hhv[j];
                float ex = __expf(2.f * h);
                s += (1.f - 2.f * __builtin_amdgcn_rcpf(ex + 1.f)) * wvv[j];
            }
            s += __shfl_xor(s, 1); s += __shfl_xor(s, 2);
            s += __shfl_xor(s, 4); s += __shfl_xor(s, 8);
            if (lane16 == 0) spl[(i * 16 + g * 4 + r) * 8 + wid] = s;
        }
    LGKM0();
    RBAR();

    // ---- softmax over S=64 (bv shift is a softmax no-op) ----
    if (tid < 64) {
        float s = ((spl[tid * 8 + 0] + spl[tid * 8 + 1]) + (spl[tid * 8 + 2] + spl[tid * 8 + 3])) +
                  ((spl[tid * 8 + 4] + spl[tid * 8 + 5]) + (spl[tid * 8 + 6] + spl[tid * 8 + 7]));
        float m = s;
        #pragma unroll
        for (int off = 32; off; off >>= 1) m = fmaxf(m, __shfl_xor(m, off));
        float e = __expf(s - m);
        float sum = e;
        #pragma unroll
        for (int off = 32; off; off >>= 1) sum += __shfl_xor(sum, off);
        wsm[tid] = e / sum;
        LGKM0();
    }
    RBAR();

    // ---- context from LDS fp16 A: thread-half x col-pair split ----
    {
        const int t2 = tid & 255, half = tid >> 8;
        const int kst = t2 >> 4;                    // ktile of col pair
        const int base = kst * 4096 + (t2 & 3) * 4;
        const int ksl = (t2 >> 2) & 3;
        float ax = 0.f, ay = 0.f;
        #pragma unroll 8
        for (int si = 0; si < 32; ++si) {
            const int s = half * 32 + si;
            unsigned vv = *(const unsigned*)(As + base + s * 64 +
                                             ((ksl ^ ((s >> 1) & 3)) << 4));
            float w = wsm[s];
            ax += w * (float)__builtin_bit_cast(_Float16, (unsigned short)(vv & 0xffffu));
            ay += w * (float)__builtin_bit_cast(_Float16, (unsigned short)(vv >> 16));
        }
        if (half == 1) { cpart[t2 * 2] = ax; cpart[t2 * 2 + 1] = ay; }
        LGKM0();
        RBAR();
        if (half == 0) {
            ax += cpart[t2 * 2]; ay += cpart[t2 * 2 + 1];
            ((float2*)out)[(size_t)bm * 256 + t2] = make_float2(ax, ay);
        }
    }
}

// ---------------------------------------------------------------------------
extern "C" void kernel_launch(void* const* d_in, const int* in_sizes, int n_in,
                              void* d_out, int out_size, void* d_ws, size_t ws_size,
                              hipStream_t stream) {
    (void)in_sizes; (void)n_in; (void)out_size; (void)ws_size;
    const float* feat   = (const float*)d_in[0];   // [2048,64,512]
    const float* hidden = (const float*)d_in[1];   // [2048,512]
    const float* W1     = (const float*)d_in[2];   // [512,512]
    const float* b1     = (const float*)d_in[3];   // [512]
    const float* W2     = (const float*)d_in[4];   // [512,512]
    const float* b2     = (const float*)d_in[5];   // [512]
    const float* Wv     = (const float*)d_in[6];   // [512,1]
    // d_in[7] = bv: softmax shift-invariant, unused.
    float* out = (float*)d_out;                    // [2048,512]

    char* ws = (char*)d_ws;
    unsigned short* w1img = (unsigned short*)(ws);            // 512 KB
    unsigned short* w2img = (unsigned short*)(ws + 524288);   // 512 KB
    float* h2 = (float*)(ws + 1048576);                       // 4 MB

    convert_w_kernel<<<dim3(512, 2), dim3(256), 0, stream>>>(W1, W2, w1img, w2img);
    h2_gemm_kernel<<<dim3(32, 2), dim3(256), 0, stream>>>(hidden, (const char*)w2img, b2, h2);
    fused_all_kernel<<<dim3(2048), dim3(512), 0, stream>>>(feat, (const char*)w1img, h2, b1, Wv, out);
}